// Round 2
// baseline (493.682 us; speedup 1.0000x reference)
//
#include <hip/hip_runtime.h>

typedef unsigned short u16;
typedef short short8 __attribute__((ext_vector_type(8)));
typedef float f32x4 __attribute__((ext_vector_type(4)));

#define LOG2E 1.44269504088896340736f

__device__ __forceinline__ u16 f2bf(float f) {
  unsigned u = __builtin_bit_cast(unsigned, f);
  u += 0x7fffu + ((u >> 16) & 1u);
  return (u16)(u >> 16);
}

// ---------------- kernel 1: x fp32 -> bf16 ----------------
__global__ __launch_bounds__(256) void k_convert_x(const float* __restrict__ x,
                                                   u16* __restrict__ xb) {
  int i = blockIdx.x * 256 + threadIdx.x;   // 8192 blocks * 256 thr * 4 elems = 8388608
  float4 v = ((const float4*)x)[i];
  ushort4 o;
  o.x = f2bf(v.x); o.y = f2bf(v.y); o.z = f2bf(v.z); o.w = f2bf(v.w);
  ((ushort4*)xb)[i] = o;
}

// ---------------- kernel 2: WcatT [640][512] bf16 ----------------
// rows 0..63  : Wq^T * (0.125*log2e)   (scale+log2e folded into q)
// rows 64..127: Wk^T
// rows 128..639: (Wv@Wo)^T
__global__ __launch_bounds__(256) void k_wcat(const float* __restrict__ Wq,
                                              const float* __restrict__ Wk,
                                              const float* __restrict__ Wv,
                                              const float* __restrict__ Wo,
                                              u16* __restrict__ wcatT) {
  __shared__ float wo[512];
  int j = blockIdx.x;
  int t = threadIdx.x;
  if (j < 64) {
    for (int c = t; c < 512; c += 256)
      wcatT[j * 512 + c] = f2bf(Wq[c * 64 + j] * (0.125f * LOG2E));
  } else if (j < 128) {
    int jj = j - 64;
    for (int c = t; c < 512; c += 256)
      wcatT[j * 512 + c] = f2bf(Wk[c * 64 + jj]);
  } else {
    int jj = j - 128;
    for (int kk = t; kk < 512; kk += 256) wo[kk] = Wo[kk * 512 + jj];
    __syncthreads();
    for (int c = t; c < 512; c += 256) {
      const float4* wr = (const float4*)(Wv + c * 512);
      float acc = 0.f;
#pragma unroll 8
      for (int kk = 0; kk < 128; kk++) {
        float4 v = wr[kk];
        acc += v.x * wo[kk * 4 + 0] + v.y * wo[kk * 4 + 1] +
               v.z * wo[kk * 4 + 2] + v.w * wo[kk * 4 + 3];
      }
      wcatT[j * 512 + c] = f2bf(acc);
    }
  }
}

// ---------------- kernel 3: QKV' GEMM [16384,512]@[512,640] ----------------
// outputs: q [16384][64] bf16, k [16384][64] bf16, vT [4*512][4096] bf16 (transposed)
__global__ __launch_bounds__(256) void k_qkv(const u16* __restrict__ xb,
                                             const u16* __restrict__ wcatT,
                                             u16* __restrict__ q,
                                             u16* __restrict__ k,
                                             u16* __restrict__ vT) {
  __shared__ u16 lds[16384];  // 32KB: A bytes [0,16384), B bytes [16384,32768)
  int tid = threadIdx.x;
  int w = tid >> 6, lane = tid & 63;
  int fr = lane & 15, fg = lane >> 4;
  int wm = w >> 1, wn = w & 1;
  int rowbase = blockIdx.y * 128;
  int jbase = blockIdx.x * 128;
  f32x4 acc[4][4] = {};

  for (int kb = 0; kb < 512; kb += 64) {
    __syncthreads();
    // stage A tile 128x64 (x rows), linear LDS dest + pre-swizzled global src
#pragma unroll
    for (int n = 0; n < 4; n++) {
      int lin = n * 4096 + tid * 16;
      int row = lin >> 7;
      int src = (((lin >> 4) & 7) * 16) ^ ((row & 7) << 4);
      const char* ga = (const char*)(xb + (size_t)(rowbase + row) * 512 + kb) + src;
      __builtin_amdgcn_global_load_lds(
          (const __attribute__((address_space(1))) void*)ga,
          (__attribute__((address_space(3))) void*)((char*)lds + n * 4096 + (w << 10)),
          16, 0, 0);
    }
    // stage B tile 128x64 (wcatT rows)
#pragma unroll
    for (int n = 0; n < 4; n++) {
      int lin = n * 4096 + tid * 16;
      int row = lin >> 7;
      int src = (((lin >> 4) & 7) * 16) ^ ((row & 7) << 4);
      const char* ga = (const char*)(wcatT + (size_t)(jbase + row) * 512 + kb) + src;
      __builtin_amdgcn_global_load_lds(
          (const __attribute__((address_space(1))) void*)ga,
          (__attribute__((address_space(3))) void*)((char*)lds + 16384 + n * 4096 + (w << 10)),
          16, 0, 0);
    }
    __syncthreads();
    short8 af[4][2], bfr[4][2];
#pragma unroll
    for (int mt = 0; mt < 4; mt++)
#pragma unroll
      for (int ks = 0; ks < 2; ks++) {
        int row = wm * 64 + mt * 16 + fr;
        int off = row * 128 + ((ks * 64 + fg * 16) ^ ((row & 7) << 4));
        af[mt][ks] = *(const short8*)((const char*)lds + off);
      }
#pragma unroll
    for (int nt = 0; nt < 4; nt++)
#pragma unroll
      for (int ks = 0; ks < 2; ks++) {
        int j = wn * 64 + nt * 16 + fr;
        int off = 16384 + j * 128 + ((ks * 64 + fg * 16) ^ ((j & 7) << 4));
        bfr[nt][ks] = *(const short8*)((const char*)lds + off);
      }
#pragma unroll
    for (int ks = 0; ks < 2; ks++)
#pragma unroll
      for (int mt = 0; mt < 4; mt++)
#pragma unroll
        for (int nt = 0; nt < 4; nt++)
          acc[mt][nt] = __builtin_amdgcn_mfma_f32_16x16x32_bf16(
              af[mt][ks], bfr[nt][ks], acc[mt][nt], 0, 0, 0);
  }

  int r0 = rowbase + wm * 64, j0 = jbase + wn * 64;
#pragma unroll
  for (int mt = 0; mt < 4; mt++)
#pragma unroll
    for (int nt = 0; nt < 4; nt++) {
      int j16 = j0 + nt * 16 + fr;
#pragma unroll
      for (int ii = 0; ii < 4; ii++) {
        int rg = r0 + mt * 16 + fg * 4 + ii;
        u16 v = f2bf(acc[mt][nt][ii]);
        if (j16 < 64) {
          q[rg * 64 + j16] = v;
        } else if (j16 < 128) {
          k[rg * 64 + (j16 - 64)] = v;
        } else {
          int c = j16 - 128;
          int bb = rg >> 12, n = rg & 4095;
          vT[((size_t)(bb * 512 + c) << 12) + n] = v;
        }
      }
    }
}

// ---------------- kernel 4: flash attention + epilogue ----------------
// 512 WGs: (b, 32-row q-block). 8 waves; wave w: S-tile (w>>2, w&3), O cols [w*64,w*64+64).
__global__ __launch_bounds__(512, 4) void k_attn(const u16* __restrict__ q,
                                                 const u16* __restrict__ k,
                                                 const u16* __restrict__ vT,
                                                 const float* __restrict__ x,
                                                 const float* __restrict__ gamma_p,
                                                 float* __restrict__ out) {
  __shared__ float S[32][68];      // fp32 scores, padded
  __shared__ u16 P[2048];          // bf16 probs [32][64], XOR-swizzled
  __shared__ float mrow[32], lrow[32], crow[32];

  int bi = blockIdx.x;
  int xcd = bi & 7;
  int b = xcd >> 1;
  int qt = ((bi >> 3) << 1) | (xcd & 1);   // bijective: 2 XCDs per batch for L2 locality
  int qbase = qt * 32;

  int tid = threadIdx.x;
  int w = tid >> 6, lane = tid & 63;
  int fr = lane & 15, fg = lane >> 4;
  int smr = w >> 2, snc = w & 3;

  if (tid < 32) { mrow[tid] = -1e30f; lrow[tid] = 0.f; }

  // Q fragments (held in registers; scores already carry 0.125*log2e via Wq)
  short8 qa[2];
  {
    int grow = (b << 12) + qbase + smr * 16 + fr;
    qa[0] = *(const short8*)(q + grow * 64 + fg * 8);
    qa[1] = *(const short8*)(q + grow * 64 + 32 + fg * 8);
  }
  f32x4 o[2][4] = {};
  const u16* kb_ptr = k + ((size_t)b << 18);  // b*4096*64
  __syncthreads();

  for (int kt = 0; kt < 64; kt++) {
    int kv0 = kt * 64;
    // ---- S tile: 2 MFMAs per wave, K frags direct from global (L2) ----
    f32x4 s = {};
    {
      int key = kv0 + snc * 16 + fr;
      const u16* kp = kb_ptr + key * 64 + fg * 8;
      short8 kb0 = *(const short8*)kp;
      short8 kb1 = *(const short8*)(kp + 32);
      s = __builtin_amdgcn_mfma_f32_16x16x32_bf16(qa[0], kb0, s, 0, 0, 0);
      s = __builtin_amdgcn_mfma_f32_16x16x32_bf16(qa[1], kb1, s, 0, 0, 0);
    }
    {
      int srow = smr * 16 + fg * 4, scol = snc * 16 + fr;
#pragma unroll
      for (int ii = 0; ii < 4; ii++) S[srow + ii][scol] = s[ii];
    }
    __syncthreads();
    // ---- online softmax: 16 threads per row ----
    {
      int row = tid >> 4, l16 = tid & 15;
      float4 sv = *(const float4*)&S[row][l16 * 4];
      float tm = fmaxf(fmaxf(sv.x, sv.y), fmaxf(sv.z, sv.w));
#pragma unroll
      for (int d = 1; d < 16; d <<= 1) tm = fmaxf(tm, __shfl_xor(tm, d));
      float mo = mrow[row];
      float mn = fmaxf(mo, tm);
      float cr = exp2f(mo - mn);
      float p0 = exp2f(sv.x - mn), p1 = exp2f(sv.y - mn);
      float p2 = exp2f(sv.z - mn), p3 = exp2f(sv.w - mn);
      float ts = p0 + p1 + p2 + p3;
#pragma unroll
      for (int d = 1; d < 16; d <<= 1) ts += __shfl_xor(ts, d);
      if (l16 == 0) {
        mrow[row] = mn;
        lrow[row] = lrow[row] * cr + ts;
        crow[row] = cr;
      }
      ushort4 pk;
      pk.x = f2bf(p0); pk.y = f2bf(p1); pk.z = f2bf(p2); pk.w = f2bf(p3);
      int boff = row * 128 + ((l16 * 8) ^ ((row & 7) << 4));
      *(ushort4*)((char*)P + boff) = pk;
    }
    __syncthreads();
    // ---- rescale (skipped when no new max) + PV ----
    {
      float cr0[2][4];
      bool need = false;
#pragma unroll
      for (int mt = 0; mt < 2; mt++)
#pragma unroll
        for (int ii = 0; ii < 4; ii++) {
          cr0[mt][ii] = crow[mt * 16 + fg * 4 + ii];
          need |= (cr0[mt][ii] != 1.0f);
        }
      if (__any((int)need)) {
#pragma unroll
        for (int mt = 0; mt < 2; mt++)
#pragma unroll
          for (int nt = 0; nt < 4; nt++)
#pragma unroll
            for (int ii = 0; ii < 4; ii++) o[mt][nt][ii] *= cr0[mt][ii];
      }
      short8 pa[2][2];
#pragma unroll
      for (int mt = 0; mt < 2; mt++)
#pragma unroll
        for (int ks = 0; ks < 2; ks++) {
          int row = mt * 16 + fr;
          int off = row * 128 + ((ks * 64 + fg * 16) ^ ((row & 7) << 4));
          pa[mt][ks] = *(const short8*)((const char*)P + off);
        }
      const u16* vbase = vT + ((size_t)(b * 512 + w * 64) << 12) + kv0;
#pragma unroll
      for (int nt = 0; nt < 4; nt++) {
        const u16* vp = vbase + ((size_t)(nt * 16 + fr) << 12) + fg * 8;
        short8 vb0 = *(const short8*)vp;
        short8 vb1 = *(const short8*)(vp + 32);
        o[0][nt] = __builtin_amdgcn_mfma_f32_16x16x32_bf16(pa[0][0], vb0, o[0][nt], 0, 0, 0);
        o[1][nt] = __builtin_amdgcn_mfma_f32_16x16x32_bf16(pa[1][0], vb0, o[1][nt], 0, 0, 0);
        o[0][nt] = __builtin_amdgcn_mfma_f32_16x16x32_bf16(pa[0][1], vb1, o[0][nt], 0, 0, 0);
        o[1][nt] = __builtin_amdgcn_mfma_f32_16x16x32_bf16(pa[1][1], vb1, o[1][nt], 0, 0, 0);
      }
    }
    __syncthreads();
  }

  // ---- epilogue: out = gamma * O/l + x ----
  float g = gamma_p[0];
  float il[2][4];
#pragma unroll
  for (int mt = 0; mt < 2; mt++)
#pragma unroll
    for (int ii = 0; ii < 4; ii++) il[mt][ii] = 1.0f / lrow[mt * 16 + fg * 4 + ii];
#pragma unroll
  for (int mt = 0; mt < 2; mt++)
#pragma unroll
    for (int nt = 0; nt < 4; nt++)
#pragma unroll
      for (int ii = 0; ii < 4; ii++) {
        int rg = (b << 12) + qbase + mt * 16 + fg * 4 + ii;
        int col = w * 64 + nt * 16 + fr;
        size_t idx = (size_t)rg * 512 + col;
        out[idx] = g * o[mt][nt][ii] * il[mt][ii] + x[idx];
      }
}

extern "C" void kernel_launch(void* const* d_in, const int* in_sizes, int n_in,
                              void* d_out, int out_size, void* d_ws, size_t ws_size,
                              hipStream_t stream) {
  const float* x  = (const float*)d_in[0];
  const float* Wq = (const float*)d_in[1];
  const float* Wk = (const float*)d_in[2];
  const float* Wv = (const float*)d_in[3];
  const float* Wo = (const float*)d_in[4];
  const float* gm = (const float*)d_in[5];
  float* out = (float*)d_out;

  char* ws = (char*)d_ws;
  u16* xb    = (u16*)(ws);                    // 16,777,216 B
  u16* wcatT = (u16*)(ws + 16777216);         //    655,360 B
  u16* q     = (u16*)(ws + 17432576);         //  2,097,152 B
  u16* k     = (u16*)(ws + 19529728);         //  2,097,152 B
  u16* vT    = (u16*)(ws + 21626880);         // 16,777,216 B  (total ~36.6 MB)

  hipLaunchKernelGGL(k_convert_x, dim3(8192), dim3(256), 0, stream, x, xb);
  hipLaunchKernelGGL(k_wcat, dim3(640), dim3(256), 0, stream, Wq, Wk, Wv, Wo, wcatT);
  hipLaunchKernelGGL(k_qkv, dim3(5, 128), dim3(256), 0, stream, xb, wcatT, q, k, vT);
  hipLaunchKernelGGL(k_attn, dim3(512), dim3(512), 0, stream, q, k, vT, x, gm, out);
}